// Round 8
// baseline (501.355 us; speedup 1.0000x reference)
//
#include <hip/hip_runtime.h>
#include <math.h>

#define HID 512
#define TW 32
#define NQ 16

// bank-swizzle for [c][16]-float LDS tiles (conflicts measured minor; keep).
#define SWZM(c) ((((c) + ((c) >> 2) + ((c) >> 4))) & 3)

#define RED6(v) { v += __shfl_xor(v, 32); v += __shfl_xor(v, 16); \
                  v += __shfl_xor(v, 8);  v += __shfl_xor(v, 4);  \
                  v += __shfl_xor(v, 2);  v += __shfl_xor(v, 1); }

// ---------------- K1: z1 = x@W1+b1 -> s1, h1 ----------------
__global__ __launch_bounds__(512) void k1_fwd(const float* __restrict__ x,
        const float* __restrict__ W1, const float* __restrict__ b1,
        float* __restrict__ s1g, float* __restrict__ h1g) {
    __shared__ float xr[TW];
    const int r = blockIdx.x;
    const int t = threadIdx.x;
    if (t < TW) xr[t] = x[r * TW + t];
    __syncthreads();
    float z = b1[t];
    #pragma unroll
    for (int k = 0; k < TW; ++k) z = fmaf(xr[k], W1[k * HID + t], z);
    float s = 1.f / (1.f + expf(-z));
    float h = fmaxf(z, 0.f) + log1pf(expf(-fabsf(z)));
    s1g[r * HID + t] = s;
    h1g[r * HID + t] = h;
}

// ---------------- K2: z2 = h1@W2+b2 -> u2 = s2*w3, d2 = s2(1-s2)*w3 ----------------
__global__ __launch_bounds__(256) void k2_z2(const float* __restrict__ h1g,
        const float* __restrict__ W2, const float* __restrict__ b2,
        const float* __restrict__ W3,
        float* __restrict__ u2g, float* __restrict__ d2g) {
    __shared__ float As[16 * 36];
    __shared__ float Bs[16 * 64];
    const int tid = threadIdx.x;
    const int r0 = blockIdx.x * 32;
    const int n0 = blockIdx.y * 64;
    const int tm = tid >> 5;
    const int tn = tid & 31;
    float acc[4][2] = {};
    const int ar = tid >> 3;
    const int ak = (tid & 7) * 2;
    const int bk = tid >> 4;
    const int bn = (tid & 15) * 4;
    for (int k0 = 0; k0 < HID; k0 += 16) {
        __syncthreads();
        float2 av = *(const float2*)&h1g[(r0 + ar) * HID + k0 + ak];
        As[(ak + 0) * 36 + ar] = av.x;
        As[(ak + 1) * 36 + ar] = av.y;
        float4 bv = *(const float4*)&W2[(k0 + bk) * HID + n0 + bn];
        *(float4*)&Bs[bk * 64 + bn] = bv;
        __syncthreads();
        #pragma unroll
        for (int k = 0; k < 16; ++k) {
            float4 a4 = *(const float4*)&As[k * 36 + tm * 4];
            float2 bb = *(const float2*)&Bs[k * 64 + tn * 2];
            acc[0][0] = fmaf(a4.x, bb.x, acc[0][0]);
            acc[0][1] = fmaf(a4.x, bb.y, acc[0][1]);
            acc[1][0] = fmaf(a4.y, bb.x, acc[1][0]);
            acc[1][1] = fmaf(a4.y, bb.y, acc[1][1]);
            acc[2][0] = fmaf(a4.z, bb.x, acc[2][0]);
            acc[2][1] = fmaf(a4.z, bb.y, acc[2][1]);
            acc[3][0] = fmaf(a4.w, bb.x, acc[3][0]);
            acc[3][1] = fmaf(a4.w, bb.y, acc[3][1]);
        }
    }
    #pragma unroll
    for (int q = 0; q < 4; ++q) {
        #pragma unroll
        for (int p = 0; p < 2; ++p) {
            int rr = r0 + tm * 4 + q;
            int nn = n0 + tn * 2 + p;
            float z = acc[q][p] + b2[nn];
            float s = 1.f / (1.f + expf(-z));
            float w3v = W3[nn];
            u2g[rr * HID + nn] = s * w3v;
            d2g[rr * HID + nn] = s * (1.f - s) * w3v;
        }
    }
}

// ---------------- K3: v = u2 @ W2^T ----------------
__global__ __launch_bounds__(256) void k3_v(const float* __restrict__ u2g,
        const float* __restrict__ W2, float* __restrict__ vg) {
    __shared__ float As[16 * 36];
    __shared__ float Bs[16 * 68];
    const int tid = threadIdx.x;
    const int r0 = blockIdx.x * 32;
    const int n0 = blockIdx.y * 64;
    const int tm = tid >> 5;
    const int tn = tid & 31;
    float acc[4][2] = {};
    const int ar = tid >> 3;
    const int ak = (tid & 7) * 2;
    const int ba = tid >> 2;
    const int bb0 = (tid & 3) * 4;
    for (int k0 = 0; k0 < HID; k0 += 16) {
        __syncthreads();
        float2 av = *(const float2*)&u2g[(r0 + ar) * HID + k0 + ak];
        As[(ak + 0) * 36 + ar] = av.x;
        As[(ak + 1) * 36 + ar] = av.y;
        float4 bv = *(const float4*)&W2[(n0 + ba) * HID + k0 + bb0];
        Bs[(bb0 + 0) * 68 + ba] = bv.x;
        Bs[(bb0 + 1) * 68 + ba] = bv.y;
        Bs[(bb0 + 2) * 68 + ba] = bv.z;
        Bs[(bb0 + 3) * 68 + ba] = bv.w;
        __syncthreads();
        #pragma unroll
        for (int k = 0; k < 16; ++k) {
            float4 a4 = *(const float4*)&As[k * 36 + tm * 4];
            float2 bb = *(const float2*)&Bs[k * 68 + tn * 2];
            acc[0][0] = fmaf(a4.x, bb.x, acc[0][0]);
            acc[0][1] = fmaf(a4.x, bb.y, acc[0][1]);
            acc[1][0] = fmaf(a4.y, bb.x, acc[1][0]);
            acc[1][1] = fmaf(a4.y, bb.y, acc[1][1]);
            acc[2][0] = fmaf(a4.z, bb.x, acc[2][0]);
            acc[2][1] = fmaf(a4.z, bb.y, acc[2][1]);
            acc[3][0] = fmaf(a4.w, bb.x, acc[3][0]);
            acc[3][1] = fmaf(a4.w, bb.y, acc[3][1]);
        }
    }
    #pragma unroll
    for (int q = 0; q < 4; ++q) {
        #pragma unroll
        for (int p = 0; p < 2; ++p) {
            vg[(r0 + tm * 4 + q) * HID + n0 + tn * 2 + p] = acc[q][p];
        }
    }
}

// ---------------- K2b: pack s/u per 2-row group ----------------
// s2pk[(r>>1)*1024 + c*2 + (r&1)] = s1[r][c]
// u2pk[...same...]                = s1[r][c] * qw[r][c],  qw = qd @ W1[:16]
__global__ __launch_bounds__(512) void k2b_pack(const float* __restrict__ x,
        const float* __restrict__ W1, const float* __restrict__ s1g,
        float* __restrict__ s2pk, float* __restrict__ u2pk) {
    __shared__ float qd[16];
    const int r = blockIdx.x;
    const int c = threadIdx.x;
    if (c < 16) qd[c] = x[r * TW + 16 + c];
    __syncthreads();
    float qw = 0.f;
    #pragma unroll
    for (int m = 0; m < 16; ++m) qw = fmaf(qd[m], W1[m * HID + c], qw);
    const float s = s1g[r * HID + c];
    const int base = (r >> 1) * 1024 + c * 2 + (r & 1);
    s2pk[base] = s;
    u2pk[base] = s * qw;
}

// ---------------- K4: 2 rows/block; ph2 operands all-LDS broadcast ----------------
// SU (512x4 = {s0,s1,u0,u1}) aliases PT's first 1024 floats: PT is written
// only in ph5, after a barrier; SU is consumed in ph2 and prefetched to regs.
#define OFF_PT   0          // 512*16 swizzled (SU aliases [0,1024))
#define OFF_W1T2 8192       // 512*16 swizzled
#define OFF_WX   16384      // 1024: [d2 | e1]
#define OFF_YW   17408      // 1024: [y*d2 | u*(1-s1)*v]
#define OFF_H2B  18432      // 2*272 (16x17)
#define OFF_XR   18976      // 64
#define OFF_G16  19040      // 32
#define OFF_RSB  19072      // 32
#define OFF_MU   19104      // 32
#define OFF_QD   19136      // 32
#define OFF_PIV  19168      // 2
#define SMEM_FLOATS 19172   // 76688 B -> 2 blocks/CU (LDS-limited)

#define ACC16(rr, t)                                   \
  acc[rr][ 0]=fmaf(a0.x,t,acc[rr][ 0]);                \
  acc[rr][ 1]=fmaf(a0.y,t,acc[rr][ 1]);                \
  acc[rr][ 2]=fmaf(a0.z,t,acc[rr][ 2]);                \
  acc[rr][ 3]=fmaf(a0.w,t,acc[rr][ 3]);                \
  acc[rr][ 4]=fmaf(a1.x,t,acc[rr][ 4]);                \
  acc[rr][ 5]=fmaf(a1.y,t,acc[rr][ 5]);                \
  acc[rr][ 6]=fmaf(a1.z,t,acc[rr][ 6]);                \
  acc[rr][ 7]=fmaf(a1.w,t,acc[rr][ 7]);                \
  acc[rr][ 8]=fmaf(a2.x,t,acc[rr][ 8]);                \
  acc[rr][ 9]=fmaf(a2.y,t,acc[rr][ 9]);                \
  acc[rr][10]=fmaf(a2.z,t,acc[rr][10]);                \
  acc[rr][11]=fmaf(a2.w,t,acc[rr][11]);                \
  acc[rr][12]=fmaf(a3.x,t,acc[rr][12]);                \
  acc[rr][13]=fmaf(a3.y,t,acc[rr][13]);                \
  acc[rr][14]=fmaf(a3.z,t,acc[rr][14]);                \
  acc[rr][15]=fmaf(a3.w,t,acc[rr][15]);

// HP16-pass macro for one ph5 source tile (per-lane reads)
#define PH5_PASS(SRC, WXOFF, YWOFF)                                          \
  _Pragma("unroll 4")                                                        \
  for (int it = 0; it < 8; ++it) {                                           \
      const int b = it * 64 + lane;                                          \
      const float wv = WX[WXOFF + b];                                        \
      const float yw = YW[YWOFF + b];                                        \
      const int m = SWZM(b);                                                 \
      const float4 eqi = *(const float4*)&SRC[b * 16 + ((qi ^ m) << 2)];     \
      const float Li0 = hiH ? eqi.z : eqi.x;                                 \
      const float Li1 = hiH ? eqi.w : eqi.y;                                 \
      const float a0v = Li0 * wv;                                            \
      const float a1v = Li1 * wv;                                            \
      tp0 = fmaf(yw, Li0, tp0);                                              \
      tp1 = fmaf(yw, Li1, tp1);                                              \
      const float4 e0 = *(const float4*)&SRC[b * 16 + ((0 ^ m) << 2)];       \
      hp0[0] = fmaf(a0v, e0.x, hp0[0]);  hp0[1] = fmaf(a0v, e0.y, hp0[1]);   \
      hp0[2] = fmaf(a0v, e0.z, hp0[2]);  hp0[3] = fmaf(a0v, e0.w, hp0[3]);   \
      hp1[0] = fmaf(a1v, e0.x, hp1[0]);  hp1[1] = fmaf(a1v, e0.y, hp1[1]);   \
      hp1[2] = fmaf(a1v, e0.z, hp1[2]);  hp1[3] = fmaf(a1v, e0.w, hp1[3]);   \
      const float4 e1 = *(const float4*)&SRC[b * 16 + ((1 ^ m) << 2)];       \
      hp0[4] = fmaf(a0v, e1.x, hp0[4]);  hp0[5] = fmaf(a0v, e1.y, hp0[5]);   \
      hp0[6] = fmaf(a0v, e1.z, hp0[6]);  hp0[7] = fmaf(a0v, e1.w, hp0[7]);   \
      hp1[4] = fmaf(a1v, e1.x, hp1[4]);  hp1[5] = fmaf(a1v, e1.y, hp1[5]);   \
      hp1[6] = fmaf(a1v, e1.z, hp1[6]);  hp1[7] = fmaf(a1v, e1.w, hp1[7]);   \
      const float4 e2 = *(const float4*)&SRC[b * 16 + ((2 ^ m) << 2)];       \
      hp0[8] = fmaf(a0v, e2.x, hp0[8]);  hp0[9] = fmaf(a0v, e2.y, hp0[9]);   \
      hp0[10] = fmaf(a0v, e2.z, hp0[10]); hp0[11] = fmaf(a0v, e2.w, hp0[11]);\
      hp1[8] = fmaf(a1v, e2.x, hp1[8]);  hp1[9] = fmaf(a1v, e2.y, hp1[9]);   \
      hp1[10] = fmaf(a1v, e2.z, hp1[10]); hp1[11] = fmaf(a1v, e2.w, hp1[11]);\
      const float4 e3 = *(const float4*)&SRC[b * 16 + ((3 ^ m) << 2)];       \
      hp0[12] = fmaf(a0v, e3.x, hp0[12]); hp0[13] = fmaf(a0v, e3.y, hp0[13]);\
      hp0[14] = fmaf(a0v, e3.z, hp0[14]); hp0[15] = fmaf(a0v, e3.w, hp0[15]);\
      hp1[12] = fmaf(a1v, e3.x, hp1[12]); hp1[13] = fmaf(a1v, e3.y, hp1[13]);\
      hp1[14] = fmaf(a1v, e3.z, hp1[14]); hp1[15] = fmaf(a1v, e3.w, hp1[15]);\
  }

// launch_bounds 2nd arg is CUDA-style min-BLOCKS/CU on this toolchain
// (confirmed: arg 4 -> VGPR cap 64, arg 2 -> cap 128).
__global__ __launch_bounds__(512, 2) void k4_main(
        const float* __restrict__ x, const float* __restrict__ W1,
        const float* __restrict__ W2,
        const float* __restrict__ s1g, const float* __restrict__ d2g,
        const float* __restrict__ vg,
        const float* __restrict__ s2pk, const float* __restrict__ u2pk,
        float* __restrict__ out) {
    __shared__ __align__(16) float sm[SMEM_FLOATS];
    const int tid = threadIdx.x;
    const int r0 = blockIdx.x * 2;
    float* PT   = sm + OFF_PT;
    float* SU   = sm + OFF_PT;      // alias; dead once ph5 starts writing PT
    float* W1T2 = sm + OFF_W1T2;
    float* WX   = sm + OFF_WX;
    float* YW   = sm + OFF_YW;
    float* H2B  = sm + OFF_H2B;
    float* XR   = sm + OFF_XR;
    float* G16  = sm + OFF_G16;
    float* RSB  = sm + OFF_RSB;
    float* MU   = sm + OFF_MU;
    float* QD   = sm + OFF_QD;
    int*   PIV  = (int*)(sm + OFF_PIV);

    const int w    = tid >> 6;
    const int lane = tid & 63;

    // ---- ph0: stage XR, W1T2 (swizzled), SU = {s0,s1,u0,u1} per column ----
    if (tid < 64) XR[tid] = x[(r0 + (tid >> 5)) * TW + (tid & 31)];
    float s1v0, s1v1, uv0, uv1;   // this thread's own column values, kept in regs
    {
        const int c = tid;
        const int m = SWZM(c);
        #pragma unroll
        for (int q = 0; q < 4; ++q) {
            float4 wv4;
            wv4.x = W1[(16 + q * 4 + 0) * HID + c];
            wv4.y = W1[(16 + q * 4 + 1) * HID + c];
            wv4.z = W1[(16 + q * 4 + 2) * HID + c];
            wv4.w = W1[(16 + q * 4 + 3) * HID + c];
            *(float4*)&W1T2[c * 16 + ((q ^ m) << 2)] = wv4;
        }
        const float2 s2 = ((const float2*)s2pk)[(size_t)blockIdx.x * 512 + c];
        const float2 u2 = ((const float2*)u2pk)[(size_t)blockIdx.x * 512 + c];
        s1v0 = s2.x; s1v1 = s2.y; uv0 = u2.x; uv1 = u2.y;
        *(float4*)&SU[c * 4] = make_float4(s2.x, s2.y, u2.x, u2.y);
    }

    // ---- ph1: g16 wave-local: wave w -> row w>>2, j in [(w&3)*4, +4) ----
    {
        const int rr1 = w >> 2;
        const int j0 = (w & 3) * 4;
        const float* srow = s1g + (size_t)(r0 + rr1) * HID;
        const float* vrow = vg + (size_t)(r0 + rr1) * HID;
        float gp[4] = {0.f, 0.f, 0.f, 0.f};
        #pragma unroll
        for (int it = 0; it < 8; ++it) {
            const int c = it * 64 + lane;
            const float sv = srow[c] * vrow[c];
            #pragma unroll
            for (int j = 0; j < 4; ++j)
                gp[j] = fmaf(W1[(j0 + j) * HID + c], sv, gp[j]);
        }
        #pragma unroll
        for (int j = 0; j < 4; ++j) { RED6(gp[j]); }
        if (lane == 0) {
            #pragma unroll
            for (int j = 0; j < 4; ++j) G16[rr1 * 16 + j0 + j] = gp[j];
        }
    }
    __syncthreads();   // W1T2 + SU visible to all before ph2

    // ---- ph2: P2 (16 rows) + y; ALL shared operands via LDS broadcast ----
    float acc[2][16];
    #pragma unroll
    for (int rr = 0; rr < 2; ++rr)
        #pragma unroll
        for (int i = 0; i < 16; ++i) acc[rr][i] = 0.f;
    float yv[2] = {0.f, 0.f};
    {
        const float* w2p = W2 + tid;
        #pragma unroll 1
        for (int c8 = 0; c8 < HID; c8 += 8) {
            float w2v[8];
            #pragma unroll
            for (int k = 0; k < 8; ++k) w2v[k] = w2p[(size_t)(c8 + k) * HID];
            #pragma unroll
            for (int k = 0; k < 8; ++k) {
                const int c = c8 + k;
                const int m = SWZM(c);
                const float4 su = *(const float4*)&SU[c * 4];
                const float4 a0 = *(const float4*)&W1T2[c * 16 + ((0 ^ m) << 2)];
                const float4 a1 = *(const float4*)&W1T2[c * 16 + ((1 ^ m) << 2)];
                const float4 a2 = *(const float4*)&W1T2[c * 16 + ((2 ^ m) << 2)];
                const float4 a3 = *(const float4*)&W1T2[c * 16 + ((3 ^ m) << 2)];
                const float w2 = w2v[k];
                yv[0] = fmaf(su.z, w2, yv[0]);
                yv[1] = fmaf(su.w, w2, yv[1]);
                const float t0 = su.x * w2;
                const float t1 = su.y * w2;
                ACC16(0, t0)
                ACC16(1, t1)
            }
        }
    }

    // ---- ph5: per row (fully unrolled rr; static acc indexing) ----
    const int i0 = 2 * w;
    const int qi = w >> 1;
    const bool hiH = (i0 & 3) == 2;
    #pragma unroll
    for (int rr = 0; rr < 2; ++rr) {
        __syncthreads();   // rr=0: everyone done reading SU; rr=1: PT reads done
        {
            const int c = tid;
            const float d2v = d2g[(size_t)(r0 + rr) * HID + c];
            const float vvv = vg[(size_t)(r0 + rr) * HID + c];
            const float s1v = rr ? s1v1 : s1v0;
            const float uv  = rr ? uv1 : uv0;
            WX[c] = d2v;
            WX[HID + c] = s1v * (1.f - s1v) * vvv;
            YW[c] = yv[rr] * d2v;
            YW[HID + c] = uv * (1.f - s1v) * vvv;
            const int m = SWZM(c);
            *(float4*)&PT[c * 16 + ((0 ^ m) << 2)] = make_float4(acc[rr][0], acc[rr][1], acc[rr][2], acc[rr][3]);
            *(float4*)&PT[c * 16 + ((1 ^ m) << 2)] = make_float4(acc[rr][4], acc[rr][5], acc[rr][6], acc[rr][7]);
            *(float4*)&PT[c * 16 + ((2 ^ m) << 2)] = make_float4(acc[rr][8], acc[rr][9], acc[rr][10], acc[rr][11]);
            *(float4*)&PT[c * 16 + ((3 ^ m) << 2)] = make_float4(acc[rr][12], acc[rr][13], acc[rr][14], acc[rr][15]);
        }
        __syncthreads();
        float hp0[16], hp1[16];
        #pragma unroll
        for (int e = 0; e < 16; ++e) { hp0[e] = 0.f; hp1[e] = 0.f; }
        float tp0 = 0.f, tp1 = 0.f;
        PH5_PASS(PT, 0, 0)
        PH5_PASS(W1T2, HID, HID)
        #pragma unroll
        for (int e = 0; e < 16; ++e) { RED6(hp0[e]); RED6(hp1[e]); }
        RED6(tp0); RED6(tp1);
        if (lane == 0) {
            float* H0 = H2B + rr * 272 + i0 * 17;
            #pragma unroll
            for (int e = 0; e < 16; ++e) { H0[e] = hp0[e]; H0[17 + e] = hp1[e]; }
            RSB[rr * 16 + i0]     = G16[rr * 16 + i0]     - tp0;
            RSB[rr * 16 + i0 + 1] = G16[rr * 16 + i0 + 1] - tp1;
        }
    }
    __syncthreads();

    // ---- solve: 2 parallel 16x16 Gaussian eliminations w/ partial pivot ----
    {
        const int row = tid >> 8;       // 0..1
        const int lt = tid & 255;
        float* A = H2B + row * 272;
        float* rs = RSB + row * 16;
        for (int k = 0; k < 16; ++k) {
            if (lt == 0) {
                int p = k; float best = fabsf(A[k * 17 + k]);
                for (int r2 = k + 1; r2 < 16; ++r2) {
                    float v2 = fabsf(A[r2 * 17 + k]);
                    if (v2 > best) { best = v2; p = r2; }
                }
                PIV[row] = p;
            }
            __syncthreads();
            const int p = PIV[row];
            if (p != k) {
                if (lt < 16) {
                    float t1 = A[k * 17 + lt]; A[k * 17 + lt] = A[p * 17 + lt]; A[p * 17 + lt] = t1;
                } else if (lt == 16) {
                    float t1 = rs[k]; rs[k] = rs[p]; rs[p] = t1;
                }
            }
            __syncthreads();
            if (lt > k && lt < 16) MU[row * 16 + lt] = A[lt * 17 + k] / A[k * 17 + k];
            __syncthreads();
            {
                const int i2 = lt >> 4;
                const int j2 = lt & 15;
                if (i2 > k) {
                    float mu = MU[row * 16 + i2];
                    if (j2 > k) A[i2 * 17 + j2] = fmaf(-mu, A[k * 17 + j2], A[i2 * 17 + j2]);
                    if (j2 == 0) rs[i2] = fmaf(-mu, rs[k], rs[i2]);
                }
            }
            __syncthreads();
        }
        for (int k = 15; k >= 0; --k) {
            if (lt == 0) QD[row * 16 + k] = rs[k] / A[k * 17 + k];
            __syncthreads();
            if (lt < k) rs[lt] = fmaf(-QD[row * 16 + k], A[lt * 17 + k], rs[lt]);
            __syncthreads();
        }
    }

    if (tid < 64) {
        const int row = tid >> 5;
        const int e = tid & 31;
        out[(r0 + row) * TW + e] = (e < 16) ? XR[row * TW + 16 + e] : QD[row * 16 + e - 16];
    }
}

extern "C" void kernel_launch(void* const* d_in, const int* in_sizes, int n_in,
                              void* d_out, int out_size, void* d_ws, size_t ws_size,
                              hipStream_t stream) {
    const float* x  = (const float*)d_in[0];
    const float* W1 = (const float*)d_in[1];
    const float* b1 = (const float*)d_in[2];
    const float* W2 = (const float*)d_in[3];
    const float* b2 = (const float*)d_in[4];
    const float* W3 = (const float*)d_in[5];
    float* out = (float*)d_out;
    float* ws = (float*)d_ws;

    float* s1g  = ws;                      // [0, 1M) floats
    float* h1g  = ws + (1u << 20);         // dead after k2
    float* u2g  = ws + 2u * (1u << 20);    // dead after k3
    float* d2g  = ws + 3u * (1u << 20);
    float* vg   = ws + 4u * (1u << 20);
    float* s2pk = h1g;                     // alias (written by k2b after k2)
    float* u2pk = u2g;                     // alias (written by k2b after k3)

    k1_fwd<<<2048, 512, 0, stream>>>(x, W1, b1, s1g, h1g);
    dim3 g2(64, 8);
    k2_z2<<<g2, 256, 0, stream>>>(h1g, W2, b2, W3, u2g, d2g);
    k3_v<<<g2, 256, 0, stream>>>(u2g, W2, vg);
    k2b_pack<<<2048, 512, 0, stream>>>(x, W1, s1g, s2pk, u2pk);
    k4_main<<<1024, 512, 0, stream>>>(x, W1, W2, s1g, d2g, vg, s2pk, u2pk, out);
}

// Round 9
// 417.367 us; speedup vs baseline: 1.2012x; 1.2012x over previous
//
#include <hip/hip_runtime.h>
#include <math.h>

#define HID 512
#define TW 32
#define NQ 16

// quad swizzle for [c][16]-float LDS tiles (needed for ph5 per-lane reads;
// broadcast reads in ph2 are conflict-free by definition but share the layout).
#define SWZM(c) ((((c) + ((c) >> 2) + ((c) >> 4))) & 3)

#define RED6(v) { v += __shfl_xor(v, 32); v += __shfl_xor(v, 16); \
                  v += __shfl_xor(v, 8);  v += __shfl_xor(v, 4);  \
                  v += __shfl_xor(v, 2);  v += __shfl_xor(v, 1); }

// ---------------- K1: z1 = x@W1+b1 -> s1, h1 ----------------
__global__ __launch_bounds__(512) void k1_fwd(const float* __restrict__ x,
        const float* __restrict__ W1, const float* __restrict__ b1,
        float* __restrict__ s1g, float* __restrict__ h1g) {
    __shared__ float xr[TW];
    const int r = blockIdx.x;
    const int t = threadIdx.x;
    if (t < TW) xr[t] = x[r * TW + t];
    __syncthreads();
    float z = b1[t];
    #pragma unroll
    for (int k = 0; k < TW; ++k) z = fmaf(xr[k], W1[k * HID + t], z);
    float s = 1.f / (1.f + expf(-z));
    float h = fmaxf(z, 0.f) + log1pf(expf(-fabsf(z)));
    s1g[r * HID + t] = s;
    h1g[r * HID + t] = h;
}

// ---------------- K2: z2 = h1@W2+b2 -> u2 = s2*w3, d2 = s2(1-s2)*w3 ----------------
__global__ __launch_bounds__(256) void k2_z2(const float* __restrict__ h1g,
        const float* __restrict__ W2, const float* __restrict__ b2,
        const float* __restrict__ W3,
        float* __restrict__ u2g, float* __restrict__ d2g) {
    __shared__ float As[16 * 36];
    __shared__ float Bs[16 * 64];
    const int tid = threadIdx.x;
    const int r0 = blockIdx.x * 32;
    const int n0 = blockIdx.y * 64;
    const int tm = tid >> 5;
    const int tn = tid & 31;
    float acc[4][2] = {};
    const int ar = tid >> 3;
    const int ak = (tid & 7) * 2;
    const int bk = tid >> 4;
    const int bn = (tid & 15) * 4;
    for (int k0 = 0; k0 < HID; k0 += 16) {
        __syncthreads();
        float2 av = *(const float2*)&h1g[(r0 + ar) * HID + k0 + ak];
        As[(ak + 0) * 36 + ar] = av.x;
        As[(ak + 1) * 36 + ar] = av.y;
        float4 bv = *(const float4*)&W2[(k0 + bk) * HID + n0 + bn];
        *(float4*)&Bs[bk * 64 + bn] = bv;
        __syncthreads();
        #pragma unroll
        for (int k = 0; k < 16; ++k) {
            float4 a4 = *(const float4*)&As[k * 36 + tm * 4];
            float2 bb = *(const float2*)&Bs[k * 64 + tn * 2];
            acc[0][0] = fmaf(a4.x, bb.x, acc[0][0]);
            acc[0][1] = fmaf(a4.x, bb.y, acc[0][1]);
            acc[1][0] = fmaf(a4.y, bb.x, acc[1][0]);
            acc[1][1] = fmaf(a4.y, bb.y, acc[1][1]);
            acc[2][0] = fmaf(a4.z, bb.x, acc[2][0]);
            acc[2][1] = fmaf(a4.z, bb.y, acc[2][1]);
            acc[3][0] = fmaf(a4.w, bb.x, acc[3][0]);
            acc[3][1] = fmaf(a4.w, bb.y, acc[3][1]);
        }
    }
    #pragma unroll
    for (int q = 0; q < 4; ++q) {
        #pragma unroll
        for (int p = 0; p < 2; ++p) {
            int rr = r0 + tm * 4 + q;
            int nn = n0 + tn * 2 + p;
            float z = acc[q][p] + b2[nn];
            float s = 1.f / (1.f + expf(-z));
            float w3v = W3[nn];
            u2g[rr * HID + nn] = s * w3v;
            d2g[rr * HID + nn] = s * (1.f - s) * w3v;
        }
    }
}

// ---------------- K3: v = u2 @ W2^T ----------------
__global__ __launch_bounds__(256) void k3_v(const float* __restrict__ u2g,
        const float* __restrict__ W2, float* __restrict__ vg) {
    __shared__ float As[16 * 36];
    __shared__ float Bs[16 * 68];
    const int tid = threadIdx.x;
    const int r0 = blockIdx.x * 32;
    const int n0 = blockIdx.y * 64;
    const int tm = tid >> 5;
    const int tn = tid & 31;
    float acc[4][2] = {};
    const int ar = tid >> 3;
    const int ak = (tid & 7) * 2;
    const int ba = tid >> 2;
    const int bb0 = (tid & 3) * 4;
    for (int k0 = 0; k0 < HID; k0 += 16) {
        __syncthreads();
        float2 av = *(const float2*)&u2g[(r0 + ar) * HID + k0 + ak];
        As[(ak + 0) * 36 + ar] = av.x;
        As[(ak + 1) * 36 + ar] = av.y;
        float4 bv = *(const float4*)&W2[(n0 + ba) * HID + k0 + bb0];
        Bs[(bb0 + 0) * 68 + ba] = bv.x;
        Bs[(bb0 + 1) * 68 + ba] = bv.y;
        Bs[(bb0 + 2) * 68 + ba] = bv.z;
        Bs[(bb0 + 3) * 68 + ba] = bv.w;
        __syncthreads();
        #pragma unroll
        for (int k = 0; k < 16; ++k) {
            float4 a4 = *(const float4*)&As[k * 36 + tm * 4];
            float2 bb = *(const float2*)&Bs[k * 68 + tn * 2];
            acc[0][0] = fmaf(a4.x, bb.x, acc[0][0]);
            acc[0][1] = fmaf(a4.x, bb.y, acc[0][1]);
            acc[1][0] = fmaf(a4.y, bb.x, acc[1][0]);
            acc[1][1] = fmaf(a4.y, bb.y, acc[1][1]);
            acc[2][0] = fmaf(a4.z, bb.x, acc[2][0]);
            acc[2][1] = fmaf(a4.z, bb.y, acc[2][1]);
            acc[3][0] = fmaf(a4.w, bb.x, acc[3][0]);
            acc[3][1] = fmaf(a4.w, bb.y, acc[3][1]);
        }
    }
    #pragma unroll
    for (int q = 0; q < 4; ++q) {
        #pragma unroll
        for (int p = 0; p < 2; ++p) {
            vg[(r0 + tm * 4 + q) * HID + n0 + tn * 2 + p] = acc[q][p];
        }
    }
}

// ---------------- K2b: pack s/u per 4-row group ----------------
// s4g[(r>>2)*2048 + c*4 + (r&3)] = s1[r][c]
// u4g[...same...]                = s1[r][c] * qw[r][c],  qw = qd @ W1[:16]
__global__ __launch_bounds__(512) void k2b_pack(const float* __restrict__ x,
        const float* __restrict__ W1, const float* __restrict__ s1g,
        float* __restrict__ s4g, float* __restrict__ u4g) {
    __shared__ float qd[16];
    const int r = blockIdx.x;
    const int c = threadIdx.x;
    if (c < 16) qd[c] = x[r * TW + 16 + c];
    __syncthreads();
    float qw = 0.f;
    #pragma unroll
    for (int m = 0; m < 16; ++m) qw = fmaf(qd[m], W1[m * HID + c], qw);
    const float s = s1g[r * HID + c];
    const int base = (r >> 2) * 2048 + c * 4 + (r & 3);
    s4g[base] = s;
    u4g[base] = s * qw;
}

// ---------------- K4: 4 rows/block; LDS-broadcast ph2; single-row ph5 passes ----------------
// SU (512x8 = {s x4, u x4}) aliases PT's first 4096 floats: PT is written only
// in ph5 (after a barrier); SU is consumed in ph2.
#define OFF_PT   0          // 512*16 swizzled (SU aliases [0,4096))
#define OFF_W1T2 8192       // 512*16 swizzled
#define OFF_WX   16384      // 1024: [d2 | e1]
#define OFF_YW   17408      // 1024: [y*d2 | u*(1-s1)*v]
#define OFF_H2B  18432      // 4*272 (16x17)
#define OFF_XR   19520      // 128
#define OFF_G16  19648      // 64
#define OFF_RSB  19712      // 64
#define OFF_MU   19776      // 64
#define OFF_QD   19840      // 64
#define OFF_PIV  19904      // 4
#define SMEM_FLOATS 19908   // 79632 B -> 2 blocks/CU (LDS-limited); 512 blocks = 1 round

#define ACC16(rr, t)                                   \
  acc[rr][ 0]=fmaf(a0.x,t,acc[rr][ 0]);                \
  acc[rr][ 1]=fmaf(a0.y,t,acc[rr][ 1]);                \
  acc[rr][ 2]=fmaf(a0.z,t,acc[rr][ 2]);                \
  acc[rr][ 3]=fmaf(a0.w,t,acc[rr][ 3]);                \
  acc[rr][ 4]=fmaf(a1.x,t,acc[rr][ 4]);                \
  acc[rr][ 5]=fmaf(a1.y,t,acc[rr][ 5]);                \
  acc[rr][ 6]=fmaf(a1.z,t,acc[rr][ 6]);                \
  acc[rr][ 7]=fmaf(a1.w,t,acc[rr][ 7]);                \
  acc[rr][ 8]=fmaf(a2.x,t,acc[rr][ 8]);                \
  acc[rr][ 9]=fmaf(a2.y,t,acc[rr][ 9]);                \
  acc[rr][10]=fmaf(a2.z,t,acc[rr][10]);                \
  acc[rr][11]=fmaf(a2.w,t,acc[rr][11]);                \
  acc[rr][12]=fmaf(a3.x,t,acc[rr][12]);                \
  acc[rr][13]=fmaf(a3.y,t,acc[rr][13]);                \
  acc[rr][14]=fmaf(a3.z,t,acc[rr][14]);                \
  acc[rr][15]=fmaf(a3.w,t,acc[rr][15]);

// one H-row partial over one 8-it source tile; hp[16]/tp live (17 regs)
#define PH5_ROW(SRC, WXOFF, YWOFF, QI)                                       \
  _Pragma("unroll 4")                                                        \
  for (int it = 0; it < 8; ++it) {                                           \
      const int b = it * 64 + lane;                                          \
      const float wv = WX[WXOFF + b];                                        \
      const float yw = YW[YWOFF + b];                                        \
      const int m = SWZM(b);                                                 \
      const float4 eqi = *(const float4*)&SRC[b * 16 + (((QI) ^ m) << 2)];   \
      const float Li = c2 ? (c1 ? eqi.w : eqi.z) : (c1 ? eqi.y : eqi.x);     \
      const float av = Li * wv;                                              \
      tp = fmaf(yw, Li, tp);                                                 \
      const float4 e0 = *(const float4*)&SRC[b * 16 + ((0 ^ m) << 2)];       \
      hp[0] = fmaf(av, e0.x, hp[0]);   hp[1] = fmaf(av, e0.y, hp[1]);        \
      hp[2] = fmaf(av, e0.z, hp[2]);   hp[3] = fmaf(av, e0.w, hp[3]);        \
      const float4 e1 = *(const float4*)&SRC[b * 16 + ((1 ^ m) << 2)];       \
      hp[4] = fmaf(av, e1.x, hp[4]);   hp[5] = fmaf(av, e1.y, hp[5]);        \
      hp[6] = fmaf(av, e1.z, hp[6]);   hp[7] = fmaf(av, e1.w, hp[7]);        \
      const float4 e2 = *(const float4*)&SRC[b * 16 + ((2 ^ m) << 2)];       \
      hp[8] = fmaf(av, e2.x, hp[8]);   hp[9] = fmaf(av, e2.y, hp[9]);        \
      hp[10] = fmaf(av, e2.z, hp[10]); hp[11] = fmaf(av, e2.w, hp[11]);      \
      const float4 e3 = *(const float4*)&SRC[b * 16 + ((3 ^ m) << 2)];       \
      hp[12] = fmaf(av, e3.x, hp[12]); hp[13] = fmaf(av, e3.y, hp[13]);      \
      hp[14] = fmaf(av, e3.z, hp[14]); hp[15] = fmaf(av, e3.w, hp[15]);      \
  }

// launch_bounds 2nd arg is CUDA-style min-BLOCKS/CU on this toolchain
// (confirmed: arg 4 -> VGPR cap 64, arg 2 -> cap 128).
__global__ __launch_bounds__(512, 2) void k4_main(
        const float* __restrict__ x, const float* __restrict__ W1,
        const float* __restrict__ W2,
        const float* __restrict__ s1g, const float* __restrict__ d2g,
        const float* __restrict__ vg,
        const float* __restrict__ s4g, const float* __restrict__ u4g,
        float* __restrict__ out) {
    __shared__ __align__(16) float sm[SMEM_FLOATS];
    const int tid = threadIdx.x;
    const int r0 = blockIdx.x * 4;
    float* PT   = sm + OFF_PT;
    float* SU   = sm + OFF_PT;      // alias; dead once ph5 starts writing PT
    float* W1T2 = sm + OFF_W1T2;
    float* WX   = sm + OFF_WX;
    float* YW   = sm + OFF_YW;
    float* H2B  = sm + OFF_H2B;
    float* XR   = sm + OFF_XR;
    float* G16  = sm + OFF_G16;
    float* RSB  = sm + OFF_RSB;
    float* MU   = sm + OFF_MU;
    float* QD   = sm + OFF_QD;
    int*   PIV  = (int*)(sm + OFF_PIV);

    const int w    = tid >> 6;
    const int lane = tid & 63;

    // ---- ph0: stage XR, W1T2 (swizzled), SU = {s x4, u x4} per column ----
    if (tid < 128) XR[tid] = x[(r0 + (tid >> 5)) * TW + (tid & 31)];
    float s1v0, s1v1, s1v2, s1v3, uv0, uv1, uv2, uv3;  // own column, in regs
    {
        const int c = tid;
        const int m = SWZM(c);
        #pragma unroll
        for (int q = 0; q < 4; ++q) {
            float4 wv4;
            wv4.x = W1[(16 + q * 4 + 0) * HID + c];
            wv4.y = W1[(16 + q * 4 + 1) * HID + c];
            wv4.z = W1[(16 + q * 4 + 2) * HID + c];
            wv4.w = W1[(16 + q * 4 + 3) * HID + c];
            *(float4*)&W1T2[c * 16 + ((q ^ m) << 2)] = wv4;
        }
        const float4 s4 = ((const float4*)s4g)[(size_t)blockIdx.x * 512 + c];
        const float4 u4 = ((const float4*)u4g)[(size_t)blockIdx.x * 512 + c];
        s1v0 = s4.x; s1v1 = s4.y; s1v2 = s4.z; s1v3 = s4.w;
        uv0 = u4.x; uv1 = u4.y; uv2 = u4.z; uv3 = u4.w;
        *(float4*)&SU[c * 8] = s4;
        *(float4*)&SU[c * 8 + 4] = u4;
    }

    // ---- ph1: g16: wave w -> row w>>1, j in [(w&1)*8, +8) ----
    {
        const int rr1 = w >> 1;
        const int j0 = (w & 1) * 8;
        const float* srow = s1g + (size_t)(r0 + rr1) * HID;
        const float* vrow = vg + (size_t)(r0 + rr1) * HID;
        float gp[8];
        #pragma unroll
        for (int j = 0; j < 8; ++j) gp[j] = 0.f;
        #pragma unroll
        for (int it = 0; it < 8; ++it) {
            const int c = it * 64 + lane;
            const float sv = srow[c] * vrow[c];
            #pragma unroll
            for (int j = 0; j < 8; ++j)
                gp[j] = fmaf(W1[(j0 + j) * HID + c], sv, gp[j]);
        }
        #pragma unroll
        for (int j = 0; j < 8; ++j) { RED6(gp[j]); }
        if (lane == 0) {
            #pragma unroll
            for (int j = 0; j < 8; ++j) G16[rr1 * 16 + j0 + j] = gp[j];
        }
    }
    __syncthreads();   // W1T2 + SU + G16 visible before ph2

    // ---- ph2: P2 (16 rows) + y, 4 rows at once; LDS-broadcast operands ----
    float acc[4][16];
    #pragma unroll
    for (int rr = 0; rr < 4; ++rr)
        #pragma unroll
        for (int i = 0; i < 16; ++i) acc[rr][i] = 0.f;
    float yv[4] = {0.f, 0.f, 0.f, 0.f};
    {
        const float* w2p = W2 + tid;
        #pragma unroll 1
        for (int c8 = 0; c8 < HID; c8 += 8) {
            float w2v[8];
            #pragma unroll
            for (int k = 0; k < 8; ++k) w2v[k] = w2p[(size_t)(c8 + k) * HID];
            #pragma unroll
            for (int k = 0; k < 8; ++k) {
                const int c = c8 + k;
                const int m = SWZM(c);
                const float4 su_s = *(const float4*)&SU[c * 8];
                const float4 su_u = *(const float4*)&SU[c * 8 + 4];
                const float4 a0 = *(const float4*)&W1T2[c * 16 + ((0 ^ m) << 2)];
                const float4 a1 = *(const float4*)&W1T2[c * 16 + ((1 ^ m) << 2)];
                const float4 a2 = *(const float4*)&W1T2[c * 16 + ((2 ^ m) << 2)];
                const float4 a3 = *(const float4*)&W1T2[c * 16 + ((3 ^ m) << 2)];
                const float w2 = w2v[k];
                yv[0] = fmaf(su_u.x, w2, yv[0]);
                yv[1] = fmaf(su_u.y, w2, yv[1]);
                yv[2] = fmaf(su_u.z, w2, yv[2]);
                yv[3] = fmaf(su_u.w, w2, yv[3]);
                const float t0 = su_s.x * w2;
                const float t1 = su_s.y * w2;
                const float t2 = su_s.z * w2;
                const float t3 = su_s.w * w2;
                ACC16(0, t0)
                ACC16(1, t1)
                ACC16(2, t2)
                ACC16(3, t3)
            }
        }
    }

    // ---- ph5: per row rr: stage; two single-row half-passes per wave ----
    const int comp = w & 3;
    const bool c1 = (comp & 1) != 0;
    const bool c2 = (comp & 2) != 0;
    const int qlo = w >> 2;          // quad of row w
    #pragma unroll
    for (int rr = 0; rr < 4; ++rr) {
        __syncthreads();   // rr=0: SU reads done; rr>0: prior PT reads done
        {
            const int c = tid;
            const float d2v = d2g[(size_t)(r0 + rr) * HID + c];
            const float vvv = vg[(size_t)(r0 + rr) * HID + c];
            const float s1v = (rr == 0) ? s1v0 : (rr == 1) ? s1v1 : (rr == 2) ? s1v2 : s1v3;
            const float uv  = (rr == 0) ? uv0  : (rr == 1) ? uv1  : (rr == 2) ? uv2  : uv3;
            WX[c] = d2v;
            WX[HID + c] = s1v * (1.f - s1v) * vvv;
            YW[c] = yv[rr] * d2v;
            YW[HID + c] = uv * (1.f - s1v) * vvv;
            const int m = SWZM(c);
            *(float4*)&PT[c * 16 + ((0 ^ m) << 2)] = make_float4(acc[rr][0], acc[rr][1], acc[rr][2], acc[rr][3]);
            *(float4*)&PT[c * 16 + ((1 ^ m) << 2)] = make_float4(acc[rr][4], acc[rr][5], acc[rr][6], acc[rr][7]);
            *(float4*)&PT[c * 16 + ((2 ^ m) << 2)] = make_float4(acc[rr][8], acc[rr][9], acc[rr][10], acc[rr][11]);
            *(float4*)&PT[c * 16 + ((3 ^ m) << 2)] = make_float4(acc[rr][12], acc[rr][13], acc[rr][14], acc[rr][15]);
        }
        __syncthreads();
        #pragma unroll
        for (int h = 0; h < 2; ++h) {
            const int i0 = 8 * h + w;         // this wave's H-row
            const int qi = 2 * h + qlo;       // its quad index
            float hp[16];
            #pragma unroll
            for (int e = 0; e < 16; ++e) hp[e] = 0.f;
            float tp = 0.f;
            PH5_ROW(PT, 0, 0, qi)
            PH5_ROW(W1T2, HID, HID, qi)
            #pragma unroll
            for (int e = 0; e < 16; ++e) { RED6(hp[e]); }
            RED6(tp);
            if (lane == 0) {
                float* H0 = H2B + rr * 272 + i0 * 17;
                #pragma unroll
                for (int e = 0; e < 16; ++e) H0[e] = hp[e];
                RSB[rr * 16 + i0] = G16[rr * 16 + i0] - tp;
            }
        }
    }
    __syncthreads();

    // ---- solve: 4 parallel 16x16 Gaussian eliminations w/ partial pivot ----
    {
        const int row = tid >> 7;
        const int lt = tid & 127;
        float* A = H2B + row * 272;
        float* rs = RSB + row * 16;
        for (int k = 0; k < 16; ++k) {
            if (lt == 0) {
                int p = k; float best = fabsf(A[k * 17 + k]);
                for (int r2 = k + 1; r2 < 16; ++r2) {
                    float v2 = fabsf(A[r2 * 17 + k]);
                    if (v2 > best) { best = v2; p = r2; }
                }
                PIV[row] = p;
            }
            __syncthreads();
            const int p = PIV[row];
            if (p != k) {
                if (lt < 16) {
                    float t1 = A[k * 17 + lt]; A[k * 17 + lt] = A[p * 17 + lt]; A[p * 17 + lt] = t1;
                } else if (lt == 16) {
                    float t1 = rs[k]; rs[k] = rs[p]; rs[p] = t1;
                }
            }
            __syncthreads();
            if (lt > k && lt < 16) MU[row * 16 + lt] = A[lt * 17 + k] / A[k * 17 + k];
            __syncthreads();
            {
                const int i2 = lt >> 3;
                const int j2 = (lt & 7) * 2;
                if (i2 > k) {
                    float mu = MU[row * 16 + i2];
                    A[i2 * 17 + j2]     = fmaf(-mu, A[k * 17 + j2],     A[i2 * 17 + j2]);
                    A[i2 * 17 + j2 + 1] = fmaf(-mu, A[k * 17 + j2 + 1], A[i2 * 17 + j2 + 1]);
                    if ((lt & 7) == 0) rs[i2] = fmaf(-mu, rs[k], rs[i2]);
                }
            }
            __syncthreads();
        }
        for (int k = 15; k >= 0; --k) {
            if (lt == 0) QD[row * 16 + k] = rs[k] / A[k * 17 + k];
            __syncthreads();
            if (lt < k) rs[lt] = fmaf(-QD[row * 16 + k], A[lt * 17 + k], rs[lt]);
            __syncthreads();
        }
    }

    if (tid < 128) {
        const int row = tid >> 5;
        const int e = tid & 31;
        out[(r0 + row) * TW + e] = (e < 16) ? XR[row * TW + 16 + e] : QD[row * 16 + e - 16];
    }
}

extern "C" void kernel_launch(void* const* d_in, const int* in_sizes, int n_in,
                              void* d_out, int out_size, void* d_ws, size_t ws_size,
                              hipStream_t stream) {
    const float* x  = (const float*)d_in[0];
    const float* W1 = (const float*)d_in[1];
    const float* b1 = (const float*)d_in[2];
    const float* W2 = (const float*)d_in[3];
    const float* b2 = (const float*)d_in[4];
    const float* W3 = (const float*)d_in[5];
    float* out = (float*)d_out;
    float* ws = (float*)d_ws;

    float* s1g = ws;                      // [0, 1M) floats
    float* h1g = ws + (1u << 20);         // dead after k2
    float* u2g = ws + 2u * (1u << 20);    // dead after k3
    float* d2g = ws + 3u * (1u << 20);
    float* vg  = ws + 4u * (1u << 20);
    float* s4g = h1g;                     // alias (written by k2b after k2)
    float* u4g = u2g;                     // alias (written by k2b after k3)

    k1_fwd<<<2048, 512, 0, stream>>>(x, W1, b1, s1g, h1g);
    dim3 g2(64, 8);
    k2_z2<<<g2, 256, 0, stream>>>(h1g, W2, b2, W3, u2g, d2g);
    k3_v<<<g2, 256, 0, stream>>>(u2g, W2, vg);
    k2b_pack<<<2048, 512, 0, stream>>>(x, W1, s1g, s4g, u4g);
    k4_main<<<512, 512, 0, stream>>>(x, W1, W2, s1g, d2g, vg, s4g, u4g, out);
}

// Round 10
// 383.653 us; speedup vs baseline: 1.3068x; 1.0879x over previous
//
#include <hip/hip_runtime.h>
#include <math.h>

#define HID 512
#define TW 32
#define NQ 16

// quad swizzle for [c][16]-float LDS tiles (ph5 per-lane reads).
#define SWZM(c) ((((c) + ((c) >> 2) + ((c) >> 4))) & 3)

#define RED6(v) { v += __shfl_xor(v, 32); v += __shfl_xor(v, 16); \
                  v += __shfl_xor(v, 8);  v += __shfl_xor(v, 4);  \
                  v += __shfl_xor(v, 2);  v += __shfl_xor(v, 1); }

// ---------------- K1: z1 = x@W1+b1 -> s1, h1 ----------------
__global__ __launch_bounds__(512) void k1_fwd(const float* __restrict__ x,
        const float* __restrict__ W1, const float* __restrict__ b1,
        float* __restrict__ s1g, float* __restrict__ h1g) {
    __shared__ float xr[TW];
    const int r = blockIdx.x;
    const int t = threadIdx.x;
    if (t < TW) xr[t] = x[r * TW + t];
    __syncthreads();
    float z = b1[t];
    #pragma unroll
    for (int k = 0; k < TW; ++k) z = fmaf(xr[k], W1[k * HID + t], z);
    float s = 1.f / (1.f + expf(-z));
    float h = fmaxf(z, 0.f) + log1pf(expf(-fabsf(z)));
    s1g[r * HID + t] = s;
    h1g[r * HID + t] = h;
}

// ---------------- K2: z2 = h1@W2+b2 -> u2 = s2*w3, d2 = s2(1-s2)*w3 ----------------
__global__ __launch_bounds__(256) void k2_z2(const float* __restrict__ h1g,
        const float* __restrict__ W2, const float* __restrict__ b2,
        const float* __restrict__ W3,
        float* __restrict__ u2g, float* __restrict__ d2g) {
    __shared__ float As[16 * 36];
    __shared__ float Bs[16 * 64];
    const int tid = threadIdx.x;
    const int r0 = blockIdx.x * 32;
    const int n0 = blockIdx.y * 64;
    const int tm = tid >> 5;
    const int tn = tid & 31;
    float acc[4][2] = {};
    const int ar = tid >> 3;
    const int ak = (tid & 7) * 2;
    const int bk = tid >> 4;
    const int bn = (tid & 15) * 4;
    for (int k0 = 0; k0 < HID; k0 += 16) {
        __syncthreads();
        float2 av = *(const float2*)&h1g[(r0 + ar) * HID + k0 + ak];
        As[(ak + 0) * 36 + ar] = av.x;
        As[(ak + 1) * 36 + ar] = av.y;
        float4 bv = *(const float4*)&W2[(k0 + bk) * HID + n0 + bn];
        *(float4*)&Bs[bk * 64 + bn] = bv;
        __syncthreads();
        #pragma unroll
        for (int k = 0; k < 16; ++k) {
            float4 a4 = *(const float4*)&As[k * 36 + tm * 4];
            float2 bb = *(const float2*)&Bs[k * 64 + tn * 2];
            acc[0][0] = fmaf(a4.x, bb.x, acc[0][0]);
            acc[0][1] = fmaf(a4.x, bb.y, acc[0][1]);
            acc[1][0] = fmaf(a4.y, bb.x, acc[1][0]);
            acc[1][1] = fmaf(a4.y, bb.y, acc[1][1]);
            acc[2][0] = fmaf(a4.z, bb.x, acc[2][0]);
            acc[2][1] = fmaf(a4.z, bb.y, acc[2][1]);
            acc[3][0] = fmaf(a4.w, bb.x, acc[3][0]);
            acc[3][1] = fmaf(a4.w, bb.y, acc[3][1]);
        }
    }
    #pragma unroll
    for (int q = 0; q < 4; ++q) {
        #pragma unroll
        for (int p = 0; p < 2; ++p) {
            int rr = r0 + tm * 4 + q;
            int nn = n0 + tn * 2 + p;
            float z = acc[q][p] + b2[nn];
            float s = 1.f / (1.f + expf(-z));
            float w3v = W3[nn];
            u2g[rr * HID + nn] = s * w3v;
            d2g[rr * HID + nn] = s * (1.f - s) * w3v;
        }
    }
}

// ---------------- K3: v = u2 @ W2^T ----------------
__global__ __launch_bounds__(256) void k3_v(const float* __restrict__ u2g,
        const float* __restrict__ W2, float* __restrict__ vg) {
    __shared__ float As[16 * 36];
    __shared__ float Bs[16 * 68];
    const int tid = threadIdx.x;
    const int r0 = blockIdx.x * 32;
    const int n0 = blockIdx.y * 64;
    const int tm = tid >> 5;
    const int tn = tid & 31;
    float acc[4][2] = {};
    const int ar = tid >> 3;
    const int ak = (tid & 7) * 2;
    const int ba = tid >> 2;
    const int bb0 = (tid & 3) * 4;
    for (int k0 = 0; k0 < HID; k0 += 16) {
        __syncthreads();
        float2 av = *(const float2*)&u2g[(r0 + ar) * HID + k0 + ak];
        As[(ak + 0) * 36 + ar] = av.x;
        As[(ak + 1) * 36 + ar] = av.y;
        float4 bv = *(const float4*)&W2[(n0 + ba) * HID + k0 + bb0];
        Bs[(bb0 + 0) * 68 + ba] = bv.x;
        Bs[(bb0 + 1) * 68 + ba] = bv.y;
        Bs[(bb0 + 2) * 68 + ba] = bv.z;
        Bs[(bb0 + 3) * 68 + ba] = bv.w;
        __syncthreads();
        #pragma unroll
        for (int k = 0; k < 16; ++k) {
            float4 a4 = *(const float4*)&As[k * 36 + tm * 4];
            float2 bb = *(const float2*)&Bs[k * 68 + tn * 2];
            acc[0][0] = fmaf(a4.x, bb.x, acc[0][0]);
            acc[0][1] = fmaf(a4.x, bb.y, acc[0][1]);
            acc[1][0] = fmaf(a4.y, bb.x, acc[1][0]);
            acc[1][1] = fmaf(a4.y, bb.y, acc[1][1]);
            acc[2][0] = fmaf(a4.z, bb.x, acc[2][0]);
            acc[2][1] = fmaf(a4.z, bb.y, acc[2][1]);
            acc[3][0] = fmaf(a4.w, bb.x, acc[3][0]);
            acc[3][1] = fmaf(a4.w, bb.y, acc[3][1]);
        }
    }
    #pragma unroll
    for (int q = 0; q < 4; ++q) {
        #pragma unroll
        for (int p = 0; p < 2; ++p) {
            vg[(r0 + tm * 4 + q) * HID + n0 + tn * 2 + p] = acc[q][p];
        }
    }
}

// ---------------- K2b: pack s/u per 4-row group; W1_2 transpose ----------------
__global__ __launch_bounds__(512) void k2b_pack(const float* __restrict__ x,
        const float* __restrict__ W1, const float* __restrict__ s1g,
        float* __restrict__ s4g, float* __restrict__ u4g,
        float* __restrict__ wt2g) {
    __shared__ float qd[16];
    const int r = blockIdx.x;
    const int c = threadIdx.x;
    if (c < 16) qd[c] = x[r * TW + 16 + c];
    __syncthreads();
    float qw = 0.f;
    #pragma unroll
    for (int m = 0; m < 16; ++m) qw = fmaf(qd[m], W1[m * HID + c], qw);
    const float s = s1g[r * HID + c];
    const int base = (r >> 2) * 2048 + c * 4 + (r & 3);
    s4g[base] = s;
    u4g[base] = s * qw;
    if (r == 0) {
        #pragma unroll
        for (int j = 0; j < 16; ++j)
            wt2g[c * 16 + j] = W1[(16 + j) * HID + c];
    }
}

// ---------------- K4: 4 rows/block; ph2 wave-uniform operands via SCALAR loads ----------------
#define OFF_PT   0          // 512*16 swizzled
#define OFF_W1T2 8192       // 512*16 swizzled
#define OFF_WX   16384      // 1024: [d2 | e1]
#define OFF_YW   17408      // 1024: [y*d2 | u*(1-s1)*v]
#define OFF_H2B  18432      // 4*272 (16x17)
#define OFF_XR   19520      // 128
#define OFF_G16  19648      // 64
#define OFF_RSB  19712      // 64
#define OFF_MU   19776      // 64
#define OFF_QD   19840      // 64
#define OFF_PIV  19904      // 4
#define SMEM_FLOATS 19908   // 79632 B -> 2 blocks/CU (LDS-limited); 512 blocks = 1 round

#define ACC16(rr, t)                                   \
  acc[rr][ 0]=fmaf(a0.x,t,acc[rr][ 0]);                \
  acc[rr][ 1]=fmaf(a0.y,t,acc[rr][ 1]);                \
  acc[rr][ 2]=fmaf(a0.z,t,acc[rr][ 2]);                \
  acc[rr][ 3]=fmaf(a0.w,t,acc[rr][ 3]);                \
  acc[rr][ 4]=fmaf(a1.x,t,acc[rr][ 4]);                \
  acc[rr][ 5]=fmaf(a1.y,t,acc[rr][ 5]);                \
  acc[rr][ 6]=fmaf(a1.z,t,acc[rr][ 6]);                \
  acc[rr][ 7]=fmaf(a1.w,t,acc[rr][ 7]);                \
  acc[rr][ 8]=fmaf(a2.x,t,acc[rr][ 8]);                \
  acc[rr][ 9]=fmaf(a2.y,t,acc[rr][ 9]);                \
  acc[rr][10]=fmaf(a2.z,t,acc[rr][10]);                \
  acc[rr][11]=fmaf(a2.w,t,acc[rr][11]);                \
  acc[rr][12]=fmaf(a3.x,t,acc[rr][12]);                \
  acc[rr][13]=fmaf(a3.y,t,acc[rr][13]);                \
  acc[rr][14]=fmaf(a3.z,t,acc[rr][14]);                \
  acc[rr][15]=fmaf(a3.w,t,acc[rr][15]);

// one H-row partial over one 8-it source tile; hp[16]/tp live (17 regs)
#define PH5_ROW(SRC, WXOFF, YWOFF, QI)                                       \
  _Pragma("unroll 4")                                                        \
  for (int it = 0; it < 8; ++it) {                                           \
      const int b = it * 64 + lane;                                          \
      const float wv = WX[WXOFF + b];                                        \
      const float yw = YW[YWOFF + b];                                        \
      const int m = SWZM(b);                                                 \
      const float4 eqi = *(const float4*)&SRC[b * 16 + (((QI) ^ m) << 2)];   \
      const float Li = c2 ? (c1 ? eqi.w : eqi.z) : (c1 ? eqi.y : eqi.x);     \
      const float av = Li * wv;                                              \
      tp = fmaf(yw, Li, tp);                                                 \
      const float4 e0 = *(const float4*)&SRC[b * 16 + ((0 ^ m) << 2)];       \
      hp[0] = fmaf(av, e0.x, hp[0]);   hp[1] = fmaf(av, e0.y, hp[1]);        \
      hp[2] = fmaf(av, e0.z, hp[2]);   hp[3] = fmaf(av, e0.w, hp[3]);        \
      const float4 e1 = *(const float4*)&SRC[b * 16 + ((1 ^ m) << 2)];       \
      hp[4] = fmaf(av, e1.x, hp[4]);   hp[5] = fmaf(av, e1.y, hp[5]);        \
      hp[6] = fmaf(av, e1.z, hp[6]);   hp[7] = fmaf(av, e1.w, hp[7]);        \
      const float4 e2 = *(const float4*)&SRC[b * 16 + ((2 ^ m) << 2)];       \
      hp[8] = fmaf(av, e2.x, hp[8]);   hp[9] = fmaf(av, e2.y, hp[9]);        \
      hp[10] = fmaf(av, e2.z, hp[10]); hp[11] = fmaf(av, e2.w, hp[11]);      \
      const float4 e3 = *(const float4*)&SRC[b * 16 + ((3 ^ m) << 2)];       \
      hp[12] = fmaf(av, e3.x, hp[12]); hp[13] = fmaf(av, e3.y, hp[13]);      \
      hp[14] = fmaf(av, e3.z, hp[14]); hp[15] = fmaf(av, e3.w, hp[15]);      \
  }

// launch_bounds 2nd arg is CUDA-style min-BLOCKS/CU on this toolchain
// (confirmed: arg 4 -> VGPR cap 64, arg 2 -> cap 128).
__global__ __launch_bounds__(512, 2) void k4_main(
        const float* __restrict__ x, const float* __restrict__ W1,
        const float* __restrict__ W2,
        const float* __restrict__ s1g, const float* __restrict__ d2g,
        const float* __restrict__ vg,
        const float* __restrict__ s4g, const float* __restrict__ u4g,
        const float* __restrict__ wt2g,
        float* __restrict__ out) {
    __shared__ __align__(16) float sm[SMEM_FLOATS];
    const int tid = threadIdx.x;
    const int r0 = blockIdx.x * 4;
    float* PT   = sm + OFF_PT;
    float* W1T2 = sm + OFF_W1T2;
    float* WX   = sm + OFF_WX;
    float* YW   = sm + OFF_YW;
    float* H2B  = sm + OFF_H2B;
    float* XR   = sm + OFF_XR;
    float* G16  = sm + OFF_G16;
    float* RSB  = sm + OFF_RSB;
    float* MU   = sm + OFF_MU;
    float* QD   = sm + OFF_QD;
    int*   PIV  = (int*)(sm + OFF_PIV);

    const int w    = tid >> 6;
    const int lane = tid & 63;

    // ---- ph0: stage XR, W1T2 (swizzled); own-column s/u into registers ----
    if (tid < 128) XR[tid] = x[(r0 + (tid >> 5)) * TW + (tid & 31)];
    float s1v0, s1v1, s1v2, s1v3, uv0, uv1, uv2, uv3;
    {
        const int c = tid;
        const int m = SWZM(c);
        #pragma unroll
        for (int q = 0; q < 4; ++q) {
            float4 wv4;
            wv4.x = W1[(16 + q * 4 + 0) * HID + c];
            wv4.y = W1[(16 + q * 4 + 1) * HID + c];
            wv4.z = W1[(16 + q * 4 + 2) * HID + c];
            wv4.w = W1[(16 + q * 4 + 3) * HID + c];
            *(float4*)&W1T2[c * 16 + ((q ^ m) << 2)] = wv4;
        }
        const float4 s4 = ((const float4*)s4g)[(size_t)blockIdx.x * 512 + c];
        const float4 u4 = ((const float4*)u4g)[(size_t)blockIdx.x * 512 + c];
        s1v0 = s4.x; s1v1 = s4.y; s1v2 = s4.z; s1v3 = s4.w;
        uv0 = u4.x; uv1 = u4.y; uv2 = u4.z; uv3 = u4.w;
    }

    // ---- ph1: g16: wave w -> row w>>1, j in [(w&1)*8, +8) ----
    {
        const int rr1 = w >> 1;
        const int j0 = (w & 1) * 8;
        const float* srow = s1g + (size_t)(r0 + rr1) * HID;
        const float* vrow = vg + (size_t)(r0 + rr1) * HID;
        float gp[8];
        #pragma unroll
        for (int j = 0; j < 8; ++j) gp[j] = 0.f;
        #pragma unroll
        for (int it = 0; it < 8; ++it) {
            const int c = it * 64 + lane;
            const float sv = srow[c] * vrow[c];
            #pragma unroll
            for (int j = 0; j < 8; ++j)
                gp[j] = fmaf(W1[(j0 + j) * HID + c], sv, gp[j]);
        }
        #pragma unroll
        for (int j = 0; j < 8; ++j) { RED6(gp[j]); }
        if (lane == 0) {
            #pragma unroll
            for (int j = 0; j < 8; ++j) G16[rr1 * 16 + j0 + j] = gp[j];
        }
    }
    __syncthreads();   // W1T2 + G16 visible before ph5 (ph2 reads no LDS)

    // ---- ph2: P2 (16 rows) + y, 4 rows at once ----
    // All broadcast operands are wave-uniform GLOBAL loads (uniform index =
    // blockIdx + loop counter) -> compiler scalarizes to s_load; they ride the
    // SMEM pipe instead of the CU-shared LDS pipe (R9's bottleneck: 6 LDS
    // broadcasts/c * 16 waves saturated LDS at ~245us/CU).
    float acc[4][16];
    #pragma unroll
    for (int rr = 0; rr < 4; ++rr)
        #pragma unroll
        for (int i = 0; i < 16; ++i) acc[rr][i] = 0.f;
    float yv[4] = {0.f, 0.f, 0.f, 0.f};
    {
        const float4* wt4 = (const float4*)wt2g;
        const float4* s44 = (const float4*)s4g + (size_t)blockIdx.x * 512;
        const float4* u44 = (const float4*)u4g + (size_t)blockIdx.x * 512;
        const float* w2p = W2 + tid;
        #pragma unroll 1
        for (int c8 = 0; c8 < HID; c8 += 8) {
            float w2v[8];
            #pragma unroll
            for (int k = 0; k < 8; ++k) w2v[k] = w2p[(size_t)(c8 + k) * HID];
            #pragma unroll
            for (int k = 0; k < 8; ++k) {
                const int c = c8 + k;
                const float4 su_s = s44[c];
                const float4 su_u = u44[c];
                const float4 a0 = wt4[c * 4 + 0];
                const float4 a1 = wt4[c * 4 + 1];
                const float4 a2 = wt4[c * 4 + 2];
                const float4 a3 = wt4[c * 4 + 3];
                const float w2 = w2v[k];
                yv[0] = fmaf(su_u.x, w2, yv[0]);
                yv[1] = fmaf(su_u.y, w2, yv[1]);
                yv[2] = fmaf(su_u.z, w2, yv[2]);
                yv[3] = fmaf(su_u.w, w2, yv[3]);
                const float t0 = su_s.x * w2;
                const float t1 = su_s.y * w2;
                const float t2 = su_s.z * w2;
                const float t3 = su_s.w * w2;
                ACC16(0, t0)
                ACC16(1, t1)
                ACC16(2, t2)
                ACC16(3, t3)
            }
        }
    }

    // ---- ph5: per row rr: stage; two single-row half-passes per wave ----
    const int comp = w & 3;
    const bool c1 = (comp & 1) != 0;
    const bool c2 = (comp & 2) != 0;
    const int qlo = w >> 2;          // quad of row w
    #pragma unroll
    for (int rr = 0; rr < 4; ++rr) {
        __syncthreads();   // rr=0: ph0 LDS writes done; rr>0: prior PT reads done
        {
            const int c = tid;
            const float d2v = d2g[(size_t)(r0 + rr) * HID + c];
            const float vvv = vg[(size_t)(r0 + rr) * HID + c];
            const float s1v = (rr == 0) ? s1v0 : (rr == 1) ? s1v1 : (rr == 2) ? s1v2 : s1v3;
            const float uv  = (rr == 0) ? uv0  : (rr == 1) ? uv1  : (rr == 2) ? uv2  : uv3;
            WX[c] = d2v;
            WX[HID + c] = s1v * (1.f - s1v) * vvv;
            YW[c] = yv[rr] * d2v;
            YW[HID + c] = uv * (1.f - s1v) * vvv;
            const int m = SWZM(c);
            *(float4*)&PT[c * 16 + ((0 ^ m) << 2)] = make_float4(acc[rr][0], acc[rr][1], acc[rr][2], acc[rr][3]);
            *(float4*)&PT[c * 16 + ((1 ^ m) << 2)] = make_float4(acc[rr][4], acc[rr][5], acc[rr][6], acc[rr][7]);
            *(float4*)&PT[c * 16 + ((2 ^ m) << 2)] = make_float4(acc[rr][8], acc[rr][9], acc[rr][10], acc[rr][11]);
            *(float4*)&PT[c * 16 + ((3 ^ m) << 2)] = make_float4(acc[rr][12], acc[rr][13], acc[rr][14], acc[rr][15]);
        }
        __syncthreads();
        #pragma unroll
        for (int h = 0; h < 2; ++h) {
            const int i0 = 8 * h + w;         // this wave's H-row
            const int qi = 2 * h + qlo;       // its quad index
            float hp[16];
            #pragma unroll
            for (int e = 0; e < 16; ++e) hp[e] = 0.f;
            float tp = 0.f;
            PH5_ROW(PT, 0, 0, qi)
            PH5_ROW(W1T2, HID, HID, qi)
            #pragma unroll
            for (int e = 0; e < 16; ++e) { RED6(hp[e]); }
            RED6(tp);
            if (lane == 0) {
                float* H0 = H2B + rr * 272 + i0 * 17;
                #pragma unroll
                for (int e = 0; e < 16; ++e) H0[e] = hp[e];
                RSB[rr * 16 + i0] = G16[rr * 16 + i0] - tp;
            }
        }
    }
    __syncthreads();

    // ---- solve: 4 parallel 16x16 Gaussian eliminations w/ partial pivot ----
    {
        const int row = tid >> 7;
        const int lt = tid & 127;
        float* A = H2B + row * 272;
        float* rs = RSB + row * 16;
        for (int k = 0; k < 16; ++k) {
            if (lt == 0) {
                int p = k; float best = fabsf(A[k * 17 + k]);
                for (int r2 = k + 1; r2 < 16; ++r2) {
                    float v2 = fabsf(A[r2 * 17 + k]);
                    if (v2 > best) { best = v2; p = r2; }
                }
                PIV[row] = p;
            }
            __syncthreads();
            const int p = PIV[row];
            if (p != k) {
                if (lt < 16) {
                    float t1 = A[k * 17 + lt]; A[k * 17 + lt] = A[p * 17 + lt]; A[p * 17 + lt] = t1;
                } else if (lt == 16) {
                    float t1 = rs[k]; rs[k] = rs[p]; rs[p] = t1;
                }
            }
            __syncthreads();
            if (lt > k && lt < 16) MU[row * 16 + lt] = A[lt * 17 + k] / A[k * 17 + k];
            __syncthreads();
            {
                const int i2 = lt >> 3;
                const int j2 = (lt & 7) * 2;
                if (i2 > k) {
                    float mu = MU[row * 16 + i2];
                    A[i2 * 17 + j2]     = fmaf(-mu, A[k * 17 + j2],     A[i2 * 17 + j2]);
                    A[i2 * 17 + j2 + 1] = fmaf(-mu, A[k * 17 + j2 + 1], A[i2 * 17 + j2 + 1]);
                    if ((lt & 7) == 0) rs[i2] = fmaf(-mu, rs[k], rs[i2]);
                }
            }
            __syncthreads();
        }
        for (int k = 15; k >= 0; --k) {
            if (lt == 0) QD[row * 16 + k] = rs[k] / A[k * 17 + k];
            __syncthreads();
            if (lt < k) rs[lt] = fmaf(-QD[row * 16 + k], A[lt * 17 + k], rs[lt]);
            __syncthreads();
        }
    }

    if (tid < 128) {
        const int row = tid >> 5;
        const int e = tid & 31;
        out[(r0 + row) * TW + e] = (e < 16) ? XR[row * TW + 16 + e] : QD[row * 16 + e - 16];
    }
}

extern "C" void kernel_launch(void* const* d_in, const int* in_sizes, int n_in,
                              void* d_out, int out_size, void* d_ws, size_t ws_size,
                              hipStream_t stream) {
    const float* x  = (const float*)d_in[0];
    const float* W1 = (const float*)d_in[1];
    const float* b1 = (const float*)d_in[2];
    const float* W2 = (const float*)d_in[3];
    const float* b2 = (const float*)d_in[4];
    const float* W3 = (const float*)d_in[5];
    float* out = (float*)d_out;
    float* ws = (float*)d_ws;

    float* s1g  = ws;                      // [0, 1M) floats
    float* h1g  = ws + (1u << 20);         // dead after k2
    float* u2g  = ws + 2u * (1u << 20);    // dead after k3
    float* d2g  = ws + 3u * (1u << 20);
    float* vg   = ws + 4u * (1u << 20);
    float* wt2g = ws + 5u * (1u << 20);    // [5M, 5M+8K)
    float* s4g  = h1g;                     // alias (written by k2b after k2)
    float* u4g  = u2g;                     // alias (written by k2b after k3)

    k1_fwd<<<2048, 512, 0, stream>>>(x, W1, b1, s1g, h1g);
    dim3 g2(64, 8);
    k2_z2<<<g2, 256, 0, stream>>>(h1g, W2, b2, W3, u2g, d2g);
    k3_v<<<g2, 256, 0, stream>>>(u2g, W2, vg);
    k2b_pack<<<2048, 512, 0, stream>>>(x, W1, s1g, s4g, u4g, wt2g);
    k4_main<<<512, 512, 0, stream>>>(x, W1, W2, s1g, d2g, vg, s4g, u4g, wt2g, out);
}

// Round 11
// 364.320 us; speedup vs baseline: 1.3761x; 1.0531x over previous
//
#include <hip/hip_runtime.h>
#include <math.h>

#define HID 512
#define TW 32
#define NQ 16

// quad swizzle for [c][16]-float LDS tiles (ph5 per-lane reads).
#define SWZM(c) ((((c) + ((c) >> 2) + ((c) >> 4))) & 3)

#define RED6(v) { v += __shfl_xor(v, 32); v += __shfl_xor(v, 16); \
                  v += __shfl_xor(v, 8);  v += __shfl_xor(v, 4);  \
                  v += __shfl_xor(v, 2);  v += __shfl_xor(v, 1); }

// ---------------- K1: z1 = x@W1+b1 -> s1, h1 ----------------
__global__ __launch_bounds__(512) void k1_fwd(const float* __restrict__ x,
        const float* __restrict__ W1, const float* __restrict__ b1,
        float* __restrict__ s1g, float* __restrict__ h1g) {
    __shared__ float xr[TW];
    const int r = blockIdx.x;
    const int t = threadIdx.x;
    if (t < TW) xr[t] = x[r * TW + t];
    __syncthreads();
    float z = b1[t];
    #pragma unroll
    for (int k = 0; k < TW; ++k) z = fmaf(xr[k], W1[k * HID + t], z);
    float s = 1.f / (1.f + expf(-z));
    float h = fmaxf(z, 0.f) + log1pf(expf(-fabsf(z)));
    s1g[r * HID + t] = s;
    h1g[r * HID + t] = h;
}

// ---------------- K2: z2 = h1@W2+b2 -> u2 = s2*w3, d2 = s2(1-s2)*w3 ----------------
__global__ __launch_bounds__(256) void k2_z2(const float* __restrict__ h1g,
        const float* __restrict__ W2, const float* __restrict__ b2,
        const float* __restrict__ W3,
        float* __restrict__ u2g, float* __restrict__ d2g) {
    __shared__ float As[16 * 36];
    __shared__ float Bs[16 * 64];
    const int tid = threadIdx.x;
    const int r0 = blockIdx.x * 32;
    const int n0 = blockIdx.y * 64;
    const int tm = tid >> 5;
    const int tn = tid & 31;
    float acc[4][2] = {};
    const int ar = tid >> 3;
    const int ak = (tid & 7) * 2;
    const int bk = tid >> 4;
    const int bn = (tid & 15) * 4;
    for (int k0 = 0; k0 < HID; k0 += 16) {
        __syncthreads();
        float2 av = *(const float2*)&h1g[(r0 + ar) * HID + k0 + ak];
        As[(ak + 0) * 36 + ar] = av.x;
        As[(ak + 1) * 36 + ar] = av.y;
        float4 bv = *(const float4*)&W2[(k0 + bk) * HID + n0 + bn];
        *(float4*)&Bs[bk * 64 + bn] = bv;
        __syncthreads();
        #pragma unroll
        for (int k = 0; k < 16; ++k) {
            float4 a4 = *(const float4*)&As[k * 36 + tm * 4];
            float2 bb = *(const float2*)&Bs[k * 64 + tn * 2];
            acc[0][0] = fmaf(a4.x, bb.x, acc[0][0]);
            acc[0][1] = fmaf(a4.x, bb.y, acc[0][1]);
            acc[1][0] = fmaf(a4.y, bb.x, acc[1][0]);
            acc[1][1] = fmaf(a4.y, bb.y, acc[1][1]);
            acc[2][0] = fmaf(a4.z, bb.x, acc[2][0]);
            acc[2][1] = fmaf(a4.z, bb.y, acc[2][1]);
            acc[3][0] = fmaf(a4.w, bb.x, acc[3][0]);
            acc[3][1] = fmaf(a4.w, bb.y, acc[3][1]);
        }
    }
    #pragma unroll
    for (int q = 0; q < 4; ++q) {
        #pragma unroll
        for (int p = 0; p < 2; ++p) {
            int rr = r0 + tm * 4 + q;
            int nn = n0 + tn * 2 + p;
            float z = acc[q][p] + b2[nn];
            float s = 1.f / (1.f + expf(-z));
            float w3v = W3[nn];
            u2g[rr * HID + nn] = s * w3v;
            d2g[rr * HID + nn] = s * (1.f - s) * w3v;
        }
    }
}

// ---------------- K3: v = u2 @ W2^T ----------------
__global__ __launch_bounds__(256) void k3_v(const float* __restrict__ u2g,
        const float* __restrict__ W2, float* __restrict__ vg) {
    __shared__ float As[16 * 36];
    __shared__ float Bs[16 * 68];
    const int tid = threadIdx.x;
    const int r0 = blockIdx.x * 32;
    const int n0 = blockIdx.y * 64;
    const int tm = tid >> 5;
    const int tn = tid & 31;
    float acc[4][2] = {};
    const int ar = tid >> 3;
    const int ak = (tid & 7) * 2;
    const int ba = tid >> 2;
    const int bb0 = (tid & 3) * 4;
    for (int k0 = 0; k0 < HID; k0 += 16) {
        __syncthreads();
        float2 av = *(const float2*)&u2g[(r0 + ar) * HID + k0 + ak];
        As[(ak + 0) * 36 + ar] = av.x;
        As[(ak + 1) * 36 + ar] = av.y;
        float4 bv = *(const float4*)&W2[(n0 + ba) * HID + k0 + bb0];
        Bs[(bb0 + 0) * 68 + ba] = bv.x;
        Bs[(bb0 + 1) * 68 + ba] = bv.y;
        Bs[(bb0 + 2) * 68 + ba] = bv.z;
        Bs[(bb0 + 3) * 68 + ba] = bv.w;
        __syncthreads();
        #pragma unroll
        for (int k = 0; k < 16; ++k) {
            float4 a4 = *(const float4*)&As[k * 36 + tm * 4];
            float2 bb = *(const float2*)&Bs[k * 68 + tn * 2];
            acc[0][0] = fmaf(a4.x, bb.x, acc[0][0]);
            acc[0][1] = fmaf(a4.x, bb.y, acc[0][1]);
            acc[1][0] = fmaf(a4.y, bb.x, acc[1][0]);
            acc[1][1] = fmaf(a4.y, bb.y, acc[1][1]);
            acc[2][0] = fmaf(a4.z, bb.x, acc[2][0]);
            acc[2][1] = fmaf(a4.z, bb.y, acc[2][1]);
            acc[3][0] = fmaf(a4.w, bb.x, acc[3][0]);
            acc[3][1] = fmaf(a4.w, bb.y, acc[3][1]);
        }
    }
    #pragma unroll
    for (int q = 0; q < 4; ++q) {
        #pragma unroll
        for (int p = 0; p < 2; ++p) {
            vg[(r0 + tm * 4 + q) * HID + n0 + tn * 2 + p] = acc[q][p];
        }
    }
}

// ---------------- K2b: pack s/u per 4-row group; W1_2 transpose ----------------
__global__ __launch_bounds__(512) void k2b_pack(const float* __restrict__ x,
        const float* __restrict__ W1, const float* __restrict__ s1g,
        float* __restrict__ s4g, float* __restrict__ u4g,
        float* __restrict__ wt2g) {
    __shared__ float qd[16];
    const int r = blockIdx.x;
    const int c = threadIdx.x;
    if (c < 16) qd[c] = x[r * TW + 16 + c];
    __syncthreads();
    float qw = 0.f;
    #pragma unroll
    for (int m = 0; m < 16; ++m) qw = fmaf(qd[m], W1[m * HID + c], qw);
    const float s = s1g[r * HID + c];
    const int base = (r >> 2) * 2048 + c * 4 + (r & 3);
    s4g[base] = s;
    u4g[base] = s * qw;
    if (r == 0) {
        #pragma unroll
        for (int j = 0; j < 16; ++j)
            wt2g[c * 16 + j] = W1[(16 + j) * HID + c];
    }
}

// ---------------- K4: 4 rows/block; scalar-operand ph2; FUSED two-row ph5 ----------------
#define OFF_PT   0          // 512*16 swizzled
#define OFF_W1T2 8192       // 512*16 swizzled
#define OFF_WX   16384      // 1024: [d2 | e1]
#define OFF_YW   17408      // 1024: [y*d2 | u*(1-s1)*v]
#define OFF_H2B  18432      // 4*272 (16x17)
#define OFF_XR   19520      // 128
#define OFF_G16  19648      // 64
#define OFF_RSB  19712      // 64
#define OFF_MU   19776      // 64
#define OFF_QD   19840      // 64
#define OFF_PIV  19904      // 4
#define SMEM_FLOATS 19908   // 79632 B

#define ACC16(rr, t)                                   \
  acc[rr][ 0]=fmaf(a0.x,t,acc[rr][ 0]);                \
  acc[rr][ 1]=fmaf(a0.y,t,acc[rr][ 1]);                \
  acc[rr][ 2]=fmaf(a0.z,t,acc[rr][ 2]);                \
  acc[rr][ 3]=fmaf(a0.w,t,acc[rr][ 3]);                \
  acc[rr][ 4]=fmaf(a1.x,t,acc[rr][ 4]);                \
  acc[rr][ 5]=fmaf(a1.y,t,acc[rr][ 5]);                \
  acc[rr][ 6]=fmaf(a1.z,t,acc[rr][ 6]);                \
  acc[rr][ 7]=fmaf(a1.w,t,acc[rr][ 7]);                \
  acc[rr][ 8]=fmaf(a2.x,t,acc[rr][ 8]);                \
  acc[rr][ 9]=fmaf(a2.y,t,acc[rr][ 9]);                \
  acc[rr][10]=fmaf(a2.z,t,acc[rr][10]);                \
  acc[rr][11]=fmaf(a2.w,t,acc[rr][11]);                \
  acc[rr][12]=fmaf(a3.x,t,acc[rr][12]);                \
  acc[rr][13]=fmaf(a3.y,t,acc[rr][13]);                \
  acc[rr][14]=fmaf(a3.z,t,acc[rr][14]);                \
  acc[rr][15]=fmaf(a3.w,t,acc[rr][15]);

// FUSED ph5 pass: one sweep of SRC columns computes BOTH H-rows (w and 8+w):
// e0..e3 read once (4 b128, no eqi re-read); Li0/Li1 extracted by wave-uniform
// selects (qloB picks quad pair, c1/c2 pick component). Halves ph5 DS traffic
// vs R10's separate h-passes (R10 bottleneck: 94us/CU of LDS pipe in ph5).
#define PH5F(SRC, OFF)                                                        \
  _Pragma("unroll 1")                                                         \
  for (int it = 0; it < 8; ++it) {                                            \
      const int b = it * 64 + lane;                                           \
      const float wv = WX[OFF + b];                                           \
      const float yw = YW[OFF + b];                                           \
      const int m = SWZM(b);                                                  \
      const float4 e0 = *(const float4*)&SRC[b * 16 + ((0 ^ m) << 2)];        \
      const float4 e1 = *(const float4*)&SRC[b * 16 + ((1 ^ m) << 2)];        \
      const float4 e2 = *(const float4*)&SRC[b * 16 + ((2 ^ m) << 2)];        \
      const float4 e3 = *(const float4*)&SRC[b * 16 + ((3 ^ m) << 2)];        \
      const float4 eqA = qloB ? e1 : e0;                                      \
      const float4 eqB = qloB ? e3 : e2;                                      \
      const float Li0 = c2 ? (c1 ? eqA.w : eqA.z) : (c1 ? eqA.y : eqA.x);     \
      const float Li1 = c2 ? (c1 ? eqB.w : eqB.z) : (c1 ? eqB.y : eqB.x);     \
      const float a0v = Li0 * wv;                                             \
      const float a1v = Li1 * wv;                                             \
      tp0 = fmaf(yw, Li0, tp0);                                               \
      tp1 = fmaf(yw, Li1, tp1);                                               \
      hp0[0] = fmaf(a0v, e0.x, hp0[0]);   hp0[1] = fmaf(a0v, e0.y, hp0[1]);   \
      hp0[2] = fmaf(a0v, e0.z, hp0[2]);   hp0[3] = fmaf(a0v, e0.w, hp0[3]);   \
      hp1[0] = fmaf(a1v, e0.x, hp1[0]);   hp1[1] = fmaf(a1v, e0.y, hp1[1]);   \
      hp1[2] = fmaf(a1v, e0.z, hp1[2]);   hp1[3] = fmaf(a1v, e0.w, hp1[3]);   \
      hp0[4] = fmaf(a0v, e1.x, hp0[4]);   hp0[5] = fmaf(a0v, e1.y, hp0[5]);   \
      hp0[6] = fmaf(a0v, e1.z, hp0[6]);   hp0[7] = fmaf(a0v, e1.w, hp0[7]);   \
      hp1[4] = fmaf(a1v, e1.x, hp1[4]);   hp1[5] = fmaf(a1v, e1.y, hp1[5]);   \
      hp1[6] = fmaf(a1v, e1.z, hp1[6]);   hp1[7] = fmaf(a1v, e1.w, hp1[7]);   \
      hp0[8] = fmaf(a0v, e2.x, hp0[8]);   hp0[9] = fmaf(a0v, e2.y, hp0[9]);   \
      hp0[10] = fmaf(a0v, e2.z, hp0[10]); hp0[11] = fmaf(a0v, e2.w, hp0[11]); \
      hp1[8] = fmaf(a1v, e2.x, hp1[8]);   hp1[9] = fmaf(a1v, e2.y, hp1[9]);   \
      hp1[10] = fmaf(a1v, e2.z, hp1[10]); hp1[11] = fmaf(a1v, e2.w, hp1[11]); \
      hp0[12] = fmaf(a0v, e3.x, hp0[12]); hp0[13] = fmaf(a0v, e3.y, hp0[13]); \
      hp0[14] = fmaf(a0v, e3.z, hp0[14]); hp0[15] = fmaf(a0v, e3.w, hp0[15]); \
      hp1[12] = fmaf(a1v, e3.x, hp1[12]); hp1[13] = fmaf(a1v, e3.y, hp1[13]); \
      hp1[14] = fmaf(a1v, e3.z, hp1[14]); hp1[15] = fmaf(a1v, e3.w, hp1[15]); \
  }

// launch_bounds 2nd arg is CUDA-style min-BLOCKS/CU on this toolchain
// (confirmed: arg 4 -> VGPR cap 64, arg 2 -> cap 128).
__global__ __launch_bounds__(512, 2) void k4_main(
        const float* __restrict__ x, const float* __restrict__ W1,
        const float* __restrict__ W2,
        const float* __restrict__ s1g, const float* __restrict__ d2g,
        const float* __restrict__ vg,
        const float* __restrict__ s4g, const float* __restrict__ u4g,
        const float* __restrict__ wt2g,
        float* __restrict__ out) {
    __shared__ __align__(16) float sm[SMEM_FLOATS];
    const int tid = threadIdx.x;
    const int r0 = blockIdx.x * 4;
    float* PT   = sm + OFF_PT;
    float* W1T2 = sm + OFF_W1T2;
    float* WX   = sm + OFF_WX;
    float* YW   = sm + OFF_YW;
    float* H2B  = sm + OFF_H2B;
    float* XR   = sm + OFF_XR;
    float* G16  = sm + OFF_G16;
    float* RSB  = sm + OFF_RSB;
    float* MU   = sm + OFF_MU;
    float* QD   = sm + OFF_QD;
    int*   PIV  = (int*)(sm + OFF_PIV);

    const int w    = tid >> 6;
    const int lane = tid & 63;

    // ---- ph0: stage XR, W1T2 (swizzled); own-column s/u into registers ----
    if (tid < 128) XR[tid] = x[(r0 + (tid >> 5)) * TW + (tid & 31)];
    float s1v0, s1v1, s1v2, s1v3, uv0, uv1, uv2, uv3;
    {
        const int c = tid;
        const int m = SWZM(c);
        #pragma unroll
        for (int q = 0; q < 4; ++q) {
            float4 wv4;
            wv4.x = W1[(16 + q * 4 + 0) * HID + c];
            wv4.y = W1[(16 + q * 4 + 1) * HID + c];
            wv4.z = W1[(16 + q * 4 + 2) * HID + c];
            wv4.w = W1[(16 + q * 4 + 3) * HID + c];
            *(float4*)&W1T2[c * 16 + ((q ^ m) << 2)] = wv4;
        }
        const float4 s4 = ((const float4*)s4g)[(size_t)blockIdx.x * 512 + c];
        const float4 u4 = ((const float4*)u4g)[(size_t)blockIdx.x * 512 + c];
        s1v0 = s4.x; s1v1 = s4.y; s1v2 = s4.z; s1v3 = s4.w;
        uv0 = u4.x; uv1 = u4.y; uv2 = u4.z; uv3 = u4.w;
    }

    // ---- ph1: g16: wave w -> row w>>1, j in [(w&1)*8, +8) ----
    {
        const int rr1 = w >> 1;
        const int j0 = (w & 1) * 8;
        const float* srow = s1g + (size_t)(r0 + rr1) * HID;
        const float* vrow = vg + (size_t)(r0 + rr1) * HID;
        float gp[8];
        #pragma unroll
        for (int j = 0; j < 8; ++j) gp[j] = 0.f;
        #pragma unroll
        for (int it = 0; it < 8; ++it) {
            const int c = it * 64 + lane;
            const float sv = srow[c] * vrow[c];
            #pragma unroll
            for (int j = 0; j < 8; ++j)
                gp[j] = fmaf(W1[(j0 + j) * HID + c], sv, gp[j]);
        }
        #pragma unroll
        for (int j = 0; j < 8; ++j) { RED6(gp[j]); }
        if (lane == 0) {
            #pragma unroll
            for (int j = 0; j < 8; ++j) G16[rr1 * 16 + j0 + j] = gp[j];
        }
    }
    __syncthreads();   // W1T2 + G16 visible before ph5 (ph2 reads no LDS)

    // ---- ph2: P2 (16 rows) + y, 4 rows at once; wave-uniform scalar loads ----
    float acc[4][16];
    #pragma unroll
    for (int rr = 0; rr < 4; ++rr)
        #pragma unroll
        for (int i = 0; i < 16; ++i) acc[rr][i] = 0.f;
    float yv[4] = {0.f, 0.f, 0.f, 0.f};
    {
        const float4* wt4 = (const float4*)wt2g;
        const float4* s44 = (const float4*)s4g + (size_t)blockIdx.x * 512;
        const float4* u44 = (const float4*)u4g + (size_t)blockIdx.x * 512;
        const float* w2p = W2 + tid;
        #pragma unroll 1
        for (int c8 = 0; c8 < HID; c8 += 8) {
            float w2v[8];
            #pragma unroll
            for (int k = 0; k < 8; ++k) w2v[k] = w2p[(size_t)(c8 + k) * HID];
            #pragma unroll
            for (int k = 0; k < 8; ++k) {
                const int c = c8 + k;
                const float4 su_s = s44[c];
                const float4 su_u = u44[c];
                const float4 a0 = wt4[c * 4 + 0];
                const float4 a1 = wt4[c * 4 + 1];
                const float4 a2 = wt4[c * 4 + 2];
                const float4 a3 = wt4[c * 4 + 3];
                const float w2 = w2v[k];
                yv[0] = fmaf(su_u.x, w2, yv[0]);
                yv[1] = fmaf(su_u.y, w2, yv[1]);
                yv[2] = fmaf(su_u.z, w2, yv[2]);
                yv[3] = fmaf(su_u.w, w2, yv[3]);
                const float t0 = su_s.x * w2;
                const float t1 = su_s.y * w2;
                const float t2 = su_s.z * w2;
                const float t3 = su_s.w * w2;
                ACC16(0, t0)
                ACC16(1, t1)
                ACC16(2, t2)
                ACC16(3, t3)
            }
        }
    }

    // ---- ph5: per row rr: stage; ONE fused pass computes rows w and 8+w ----
    const int comp = w & 3;
    const bool c1 = (comp & 1) != 0;
    const bool c2 = (comp & 2) != 0;
    const bool qloB = (w >> 2) != 0;
    #pragma unroll
    for (int rr = 0; rr < 4; ++rr) {
        __syncthreads();   // rr=0: ph0 LDS writes done; rr>0: prior PT reads done
        {
            const int c = tid;
            const float d2v = d2g[(size_t)(r0 + rr) * HID + c];
            const float vvv = vg[(size_t)(r0 + rr) * HID + c];
            const float s1v = (rr == 0) ? s1v0 : (rr == 1) ? s1v1 : (rr == 2) ? s1v2 : s1v3;
            const float uv  = (rr == 0) ? uv0  : (rr == 1) ? uv1  : (rr == 2) ? uv2  : uv3;
            WX[c] = d2v;
            WX[HID + c] = s1v * (1.f - s1v) * vvv;
            YW[c] = yv[rr] * d2v;
            YW[HID + c] = uv * (1.f - s1v) * vvv;
            const int m = SWZM(c);
            *(float4*)&PT[c * 16 + ((0 ^ m) << 2)] = make_float4(acc[rr][0], acc[rr][1], acc[rr][2], acc[rr][3]);
            *(float4*)&PT[c * 16 + ((1 ^ m) << 2)] = make_float4(acc[rr][4], acc[rr][5], acc[rr][6], acc[rr][7]);
            *(float4*)&PT[c * 16 + ((2 ^ m) << 2)] = make_float4(acc[rr][8], acc[rr][9], acc[rr][10], acc[rr][11]);
            *(float4*)&PT[c * 16 + ((3 ^ m) << 2)] = make_float4(acc[rr][12], acc[rr][13], acc[rr][14], acc[rr][15]);
        }
        __syncthreads();
        float hp0[16], hp1[16];
        #pragma unroll
        for (int e = 0; e < 16; ++e) { hp0[e] = 0.f; hp1[e] = 0.f; }
        float tp0 = 0.f, tp1 = 0.f;
        PH5F(PT, 0)
        PH5F(W1T2, HID)
        #pragma unroll
        for (int e = 0; e < 16; ++e) { RED6(hp0[e]); RED6(hp1[e]); }
        RED6(tp0); RED6(tp1);
        if (lane == 0) {
            float* HA = H2B + rr * 272 + w * 17;
            float* HB = H2B + rr * 272 + (8 + w) * 17;
            #pragma unroll
            for (int e = 0; e < 16; ++e) { HA[e] = hp0[e]; HB[e] = hp1[e]; }
            RSB[rr * 16 + w]     = G16[rr * 16 + w]     - tp0;
            RSB[rr * 16 + 8 + w] = G16[rr * 16 + 8 + w] - tp1;
        }
    }
    __syncthreads();

    // ---- solve: 4 parallel 16x16 Gaussian eliminations w/ partial pivot ----
    {
        const int row = tid >> 7;
        const int lt = tid & 127;
        float* A = H2B + row * 272;
        float* rs = RSB + row * 16;
        for (int k = 0; k < 16; ++k) {
            if (lt == 0) {
                int p = k; float best = fabsf(A[k * 17 + k]);
                for (int r2 = k + 1; r2 < 16; ++r2) {
                    float v2 = fabsf(A[r2 * 17 + k]);
                    if (v2 > best) { best = v2; p = r2; }
                }
                PIV[row] = p;
            }
            __syncthreads();
            const int p = PIV[row];
            if (p != k) {
                if (lt < 16) {
                    float t1 = A[k * 17 + lt]; A[k * 17 + lt] = A[p * 17 + lt]; A[p * 17 + lt] = t1;
                } else if (lt == 16) {
                    float t1 = rs[k]; rs[k] = rs[p]; rs[p] = t1;
                }
            }
            __syncthreads();
            if (lt > k && lt < 16) MU[row * 16 + lt] = A[lt * 17 + k] / A[k * 17 + k];
            __syncthreads();
            {
                const int i2 = lt >> 3;
                const int j2 = (lt & 7) * 2;
                if (i2 > k) {
                    float mu = MU[row * 16 + i2];
                    A[i2 * 17 + j2]     = fmaf(-mu, A[k * 17 + j2],     A[i2 * 17 + j2]);
                    A[i2 * 17 + j2 + 1] = fmaf(-mu, A[k * 17 + j2 + 1], A[i2 * 17 + j2 + 1]);
                    if ((lt & 7) == 0) rs[i2] = fmaf(-mu, rs[k], rs[i2]);
                }
            }
            __syncthreads();
        }
        for (int k = 15; k >= 0; --k) {
            if (lt == 0) QD[row * 16 + k] = rs[k] / A[k * 17 + k];
            __syncthreads();
            if (lt < k) rs[lt] = fmaf(-QD[row * 16 + k], A[lt * 17 + k], rs[lt]);
            __syncthreads();
        }
    }

    if (tid < 128) {
        const int row = tid >> 5;
        const int e = tid & 31;
        out[(r0 + row) * TW + e] = (e < 16) ? XR[row * TW + 16 + e] : QD[row * 16 + e - 16];
    }
}

extern "C" void kernel_launch(void* const* d_in, const int* in_sizes, int n_in,
                              void* d_out, int out_size, void* d_ws, size_t ws_size,
                              hipStream_t stream) {
    const float* x  = (const float*)d_in[0];
    const float* W1 = (const float*)d_in[1];
    const float* b1 = (const float*)d_in[2];
    const float* W2 = (const float*)d_in[3];
    const float* b2 = (const float*)d_in[4];
    const float* W3 = (const float*)d_in[5];
    float* out = (float*)d_out;
    float* ws = (float*)d_ws;

    float* s1g  = ws;                      // [0, 1M) floats
    float* h1g  = ws + (1u << 20);         // dead after k2
    float* u2g  = ws + 2u * (1u << 20);    // dead after k3
    float* d2g  = ws + 3u * (1u << 20);
    float* vg   = ws + 4u * (1u << 20);
    float* wt2g = ws + 5u * (1u << 20);    // [5M, 5M+8K)
    float* s4g  = h1g;                     // alias (written by k2b after k2)
    float* u4g  = u2g;                     // alias (written by k2b after k3)

    k1_fwd<<<2048, 512, 0, stream>>>(x, W1, b1, s1g, h1g);
    dim3 g2(64, 8);
    k2_z2<<<g2, 256, 0, stream>>>(h1g, W2, b2, W3, u2g, d2g);
    k3_v<<<g2, 256, 0, stream>>>(u2g, W2, vg);
    k2b_pack<<<2048, 512, 0, stream>>>(x, W1, s1g, s4g, u4g, wt2g);
    k4_main<<<512, 512, 0, stream>>>(x, W1, W2, s1g, d2g, vg, s4g, u4g, wt2g, out);
}